// Round 14
// baseline (1989.098 us; speedup 1.0000x reference)
//
#include <hip/hip_runtime.h>

// LSTM B=1024, T=256, H=256, fp32-accurate via bf16x2-split (3-term) MFMA. v14.
// Sync redesign: h exchanged as u64 = (tag = t+1)<<32 | packed bf16x2 via
// agent-scope coherent atomics. Consumers poll DATA tags directly ->
// ONE L3 leg per exchange (no flags, no vmcnt(0), no tid0 release).
// Race-freedom: consumer at sub-step s saw tag t from ALL partners => all
// partners completed their (t-1) staging reads (program order + their
// sub-step barrier) => our tag-(t+1) overwrite of buf[(t+1)&1] is safe;
// skew between partners is bounded to 1 step by the same argument.
//
// Latency hiding: each block runs TWO independent 16-row LSTM chains (A,B),
// alternating sub-steps [stageA|barrier|mfmaA+phaseBA][stageB|...]: partner's
// A-stores fly to L3 during our B-sub-step -> polls hit on first try.
//
// Grid 256 = 32 block-rows (32 rows = chain A rows 0-15, chain B rows 16-31)
// x 8 colgroups (32 hcols). Block 512 thr = 8 waves; wave = full K=256 for
// 16 gatecols (4 hcols x 4 gates) via 16x16x32 MFMA:
//   A[row=lane&15, k=ks*32+(lane>>4)*8+e], D[col=lane&15, row=(lane>>4)*4+reg].
// Weights: 8 ksteps x 2 bf16 splits x short8 = 64 VGPR/lane (512thr/2wv-SIMD
// -> 256-VGPR cap; v8 proved frags stay resident at this shape).
// LDS planes [ch][ks][lane][16B] LINEAR: stage writes and MFMA reads each
// hit distinct 16B slots of a 1KB block -> conflict-free, no swizzle.
// Wave wv stages slice wv (hcols [32wv,32wv+32) = kstep wv); wv==cg reads own
// cols from hown LDS. 2 barriers per step (1 per sub-step).

#define Bsz   1024
#define Tt    256
#define Hh    256
#define NCLS  10
#define NTHR  512
#define HSZ64 ((size_t)Bsz * Hh)      // u64 elems per buffer

typedef float f32x4 __attribute__((ext_vector_type(4)));
typedef short s16x8 __attribute__((ext_vector_type(8)));
typedef unsigned int u32;
typedef unsigned long long u64;

// LDS: chain planes 2 x (8KB lo + 8KB hi) = 32KB | hown 2 x 16 x 36 u32
#define HOWNB  32768
#define SMEMB  (32768 + 2 * 576 * 4)

__device__ __forceinline__ unsigned short f2bf(float f) {   // RNE f32->bf16
    u32 u = __builtin_bit_cast(u32, f);
    return (unsigned short)((u + 0x7FFFu + ((u >> 16) & 1u)) >> 16);
}
__device__ __forceinline__ float bf2f(unsigned short b) {
    u32 u = ((u32)b) << 16;
    return __builtin_bit_cast(float, u);
}
template<int CTRL>
__device__ __forceinline__ float quadf(float v) {
    return __builtin_bit_cast(float,
        __builtin_amdgcn_update_dpp(0, __builtin_bit_cast(int, v),
                                    CTRL, 0xF, 0xF, true));
}
__device__ __forceinline__ float fast_tanh(float v) {
    const float e = __expf(-2.0f * fabsf(v));
    const float t = (1.0f - e) * __builtin_amdgcn_rcpf(1.0f + e);
    return copysignf(t, v);
}
__device__ __forceinline__ u64 coh_load64(const u64* p) {
    return __hip_atomic_load((u64*)p, __ATOMIC_RELAXED, __HIP_MEMORY_SCOPE_AGENT);
}
__device__ __forceinline__ void coh_store64(u64* p, u64 v) {
    __hip_atomic_store(p, v, __ATOMIC_RELAXED, __HIP_MEMORY_SCOPE_AGENT);
}

extern "C" __global__ void __launch_bounds__(NTHR, 2)
lstm_v14(const float* __restrict__ x,
         const float* __restrict__ W_gx, const float* __restrict__ W_gh, const float* __restrict__ b_g,
         const float* __restrict__ W_ix, const float* __restrict__ W_ih, const float* __restrict__ b_i,
         const float* __restrict__ W_fx, const float* __restrict__ W_fh, const float* __restrict__ b_f,
         const float* __restrict__ W_ox, const float* __restrict__ W_oh, const float* __restrict__ b_o,
         const float* __restrict__ W_ph, const float* __restrict__ b_p,
         float* __restrict__ out, u64* __restrict__ hx)
{
    __shared__ __align__(16) char smem[SMEMB];
    u32* hown = (u32*)(smem + HOWNB);       // [ch][row16][36] packed u32

    const int tid  = threadIdx.x;
    const int lane = tid & 63;
    const int wv   = tid >> 6;              // 0..7: MFMA col-tile AND staged slice
    const int br   = blockIdx.x & 31;       // block-row (32 rows)
    const int cg   = blockIdx.x >> 5;       // colgroup 0..7 (32 hcols)
    const int r0   = br * 32;

    const int gate   = lane & 3;
    const int hcol_l = wv * 4 + ((lane & 15) >> 2);    // 0..31
    const int hcol_g = cg * 32 + hcol_l;
    const int krow   = lane >> 4;                      // 0..3

    // ---- weights: split once, 8 ksteps x 2 planes = 64 VGPR/lane ----
    const float* __restrict__ Wg =
        (gate == 0) ? W_gh : (gate == 1) ? W_ih : (gate == 2) ? W_fh : W_oh;
    s16x8 bw1[8], bw2[8];
    #pragma unroll
    for (int ks = 0; ks < 8; ++ks) {
        s16x8 v1, v2;
        #pragma unroll
        for (int e = 0; e < 8; ++e) {
            const float w = Wg[(size_t)(ks * 32 + krow * 8 + e) * Hh + hcol_g];
            const unsigned short c1 = f2bf(w);
            const unsigned short c2 = f2bf(w - bf2f(c1));
            v1[e] = (short)c1; v2[e] = (short)c2;
        }
        bw1[ks] = v1; bw2[ks] = v2;
    }

    // reference bias swap preserved: f-gate uses b_o, o-gate uses b_f
    const float wx = ((gate == 0) ? W_gx : (gate == 1) ? W_ix : (gate == 2) ? W_fx : W_ox)[hcol_g];
    const float bb = ((gate == 0) ? b_g  : (gate == 1) ? b_i  : (gate == 2) ? b_o  : b_f )[hcol_g];
    float cA[4], cB[4];
    #pragma unroll
    for (int r = 0; r < 4; ++r) { cA[r] = 0.0f; cB[r] = 0.0f; }

    // staging lane map: slice = 16 rows x 32 u64-cols; 4 lanes/row, 8 u64/lane
    const int sr = lane >> 2;               // 0..15
    const int c8 = (lane & 3) * 8;          // u64 col within slice

    for (int i = tid; i < 2 * 576; i += NTHR) hown[i] = 0u;   // h0 = 0
    __syncthreads();

    // one sub-step of one chain (ch is a literal at both call sites)
    auto substep = [&](int t, int ch, float* cst) {
        // ---- stage slice wv of chain ch ----
        u32 packed[8];
        if (wv != cg) {
            const u64* src = hx + (size_t)(t & 1) * HSZ64
                           + (size_t)(r0 + ch * 16 + sr) * Hh + wv * 32 + c8;
            u64 q[8];
            for (;;) {
                #pragma unroll
                for (int i = 0; i < 8; ++i) q[i] = coh_load64(src + i);
                bool ok = true;
                #pragma unroll
                for (int i = 0; i < 8; ++i) ok = ok && ((u32)(q[i] >> 32) == (u32)t);
                if (__all(ok)) break;
                __builtin_amdgcn_s_sleep(1);
            }
            #pragma unroll
            for (int i = 0; i < 8; ++i) packed[i] = (u32)q[i];
        } else {
            const u32* hp = hown + ch * 576 + sr * 36 + c8;
            const uint4 q0 = *(const uint4*)hp;
            const uint4 q1 = *(const uint4*)(hp + 4);
            packed[0] = q0.x; packed[1] = q0.y; packed[2] = q0.z; packed[3] = q0.w;
            packed[4] = q1.x; packed[5] = q1.y; packed[6] = q1.z; packed[7] = q1.w;
        }
        // split into linear frag-order planes: slot (lane&3)*16 + sr of kstep wv
        {
            u32 lo[4], hi[4];
            #pragma unroll
            for (int i = 0; i < 4; ++i) {
                const u32 p0 = packed[2 * i], p1 = packed[2 * i + 1];
                lo[i] = (p0 & 0xffffu) | (p1 << 16);
                hi[i] = (p0 >> 16)     | (p1 & 0xffff0000u);
            }
            char* pb = smem + ch * 16384 + wv * 1024 + ((((lane & 3) << 4) + sr) << 4);
            *(uint4*)pb          = *(uint4*)lo;
            *(uint4*)(pb + 8192) = *(uint4*)hi;
        }
        __syncthreads();                          // planes(ch) ready; prev reads done

        // ---- MFMA: 8 ksteps x 3 split-terms, 3 independent chains ----
        f32x4 aA = {0.f,0.f,0.f,0.f}, aB = {0.f,0.f,0.f,0.f}, aC = {0.f,0.f,0.f,0.f};
        #pragma unroll
        for (int ks = 0; ks < 8; ++ks) {
            const char* ab = smem + ch * 16384 + ks * 1024 + lane * 16;
            const s16x8 a1 = *(const s16x8*)ab;
            const s16x8 a2 = *(const s16x8*)(ab + 8192);
            aA = __builtin_amdgcn_mfma_f32_16x16x32_bf16(a1, bw1[ks], aA, 0, 0, 0);
            aB = __builtin_amdgcn_mfma_f32_16x16x32_bf16(a2, bw1[ks], aB, 0, 0, 0);
            aC = __builtin_amdgcn_mfma_f32_16x16x32_bf16(a1, bw2[ks], aC, 0, 0, 0);
        }
        const f32x4 acc = aA + aB + aC;

        // ---- phase B: 4 states/lane ----
        #pragma unroll
        for (int r = 0; r < 4; ++r) {
            const int rowl = krow * 4 + r;
            const int row  = ch * 16 + rowl;
            const float xval = x[(size_t)(r0 + row) * Tt + t];
            const float pre  = acc[r] + fmaf(xval, wx, bb);
            const float vin  = (gate == 0) ? 2.0f * pre : pre;
            const float e    = __expf(-fabsf(vin));
            const float rc   = __builtin_amdgcn_rcpf(1.0f + e);
            const float sig  = (vin >= 0.0f) ? rc : 1.0f - rc;
            const float th   = copysignf((1.0f - e) * rc, pre);
            const float act  = (gate == 0) ? th : sig;
            const float gv = quadf<0x00>(act);
            const float iv = quadf<0x55>(act);
            const float fv = quadf<0xAA>(act);
            const float ov = quadf<0xFF>(act);
            cst[r] = fmaf(gv, iv, cst[r] * fv);
            const float hv = fast_tanh(cst[r]) * ov;
            if (gate == 0) {
                const unsigned short h1 = f2bf(hv);
                const unsigned short h2 = f2bf(hv - bf2f(h1));
                const u32 pk = (u32)h1 | ((u32)h2 << 16);
                coh_store64(hx + (size_t)((t + 1) & 1) * HSZ64
                               + (size_t)(r0 + row) * Hh + hcol_g,
                            ((u64)(u32)(t + 1) << 32) | (u64)pk);
                hown[ch * 576 + rowl * 36 + hcol_l] = pk;
            }
        }
    };

    for (int t = 0; t < Tt; ++t) {
        substep(t, 0, cA);
        substep(t, 1, cB);
    }

    // ---- classifier (cg==0): out = h_T @ W_ph + b_p; h(256) tag=256 in buf0 ----
    if (cg == 0) {
        __syncthreads();
        u32* tile = (u32*)smem;                        // [32][256] packed h_T
        const u64* src = hx + (size_t)r0 * Hh;         // buffer 0
        for (int i = tid; i < 32 * Hh; i += NTHR) {
            u64 q = coh_load64(src + i);
            while ((u32)(q >> 32) != (u32)Tt) {
                __builtin_amdgcn_s_sleep(1);
                q = coh_load64(src + i);
            }
            tile[i] = (u32)q;
        }
        __syncthreads();
        for (int idx = tid; idx < 32 * NCLS; idx += NTHR) {
            const int row = idx / NCLS;
            const int cc  = idx - row * NCLS;
            float a = b_p[cc];
            for (int k = 0; k < Hh; ++k) {
                const u32 p = tile[row * Hh + k];
                a = fmaf(bf2f((unsigned short)p) + bf2f((unsigned short)(p >> 16)),
                         W_ph[k * NCLS + cc], a);
            }
            out[(size_t)(r0 + row) * NCLS + cc] = a;
        }
    }
}

extern "C" void kernel_launch(void* const* d_in, const int* in_sizes, int n_in,
                              void* d_out, int out_size, void* d_ws, size_t ws_size,
                              hipStream_t stream) {
    const float* x    = (const float*)d_in[0];
    const float* W_gx = (const float*)d_in[1];
    const float* W_gh = (const float*)d_in[2];
    const float* b_g  = (const float*)d_in[3];
    const float* W_ix = (const float*)d_in[4];
    const float* W_ih = (const float*)d_in[5];
    const float* b_i  = (const float*)d_in[6];
    const float* W_fx = (const float*)d_in[7];
    const float* W_fh = (const float*)d_in[8];
    const float* b_f  = (const float*)d_in[9];
    const float* W_ox = (const float*)d_in[10];
    const float* W_oh = (const float*)d_in[11];
    const float* b_o  = (const float*)d_in[12];
    const float* W_ph = (const float*)d_in[13];
    const float* b_p  = (const float*)d_in[14];
    float* out = (float*)d_out;

    u64* hx = (u64*)d_ws;                                // 2 x 2 MB tagged ping-pong
    const size_t clear_bytes = 2 * HSZ64 * sizeof(u64);  // tags=0 == h(0) ready

    hipMemsetAsync(d_ws, 0, clear_bytes, stream);

    lstm_v14<<<dim3(256), dim3(NTHR), 0, stream>>>(
        x, W_gx, W_gh, b_g, W_ix, W_ih, b_i, W_fx, W_fh, b_f,
        W_ox, W_oh, b_o, W_ph, b_p, out, hx);
}

// Round 16
// 1752.453 us; speedup vs baseline: 1.1350x; 1.1350x over previous
//
#include <hip/hip_runtime.h>

// LSTM B=1024, T=256, H=256, fp32-accurate via bf16x2-split (3-term) MFMA. v16.
// NEW STRUCTURE: one kernel per timestep (256 step kernels + prep + head, all
// captured in the harness's graph). Kernel boundaries provide the cross-block
// h(t) handoff (dispatch barrier + cache writeback/invalidate) -- NO atomics,
// NO polling, NO spin loops, no deadlock surface. 15 rounds showed the
// in-kernel device-scope exchange chain costs ~6us/step (HBM latency legs);
// the CP's dependent-dispatch gap (~1.5-3us) replaces it.
//
// Step kernel: grid 256 = 64? no: 32 rowgroups (32 rows) x 8 colgroups
// (32 hcols); cg = bid&7 so all 32 blocks of an XCD (round-robin bid%8) share
// one 128KB pre-split weight slice (L2-friendly). Block 512 thr = 8 waves;
// wave = full K=256 for 16 gatecols (4 hcols x 4 gates) x 2 row-halves via
// 16x16x32 MFMA (A row=lane&15, k=ks*32+(lane>>4)*8+e; D col=lane&15,
// row=(lane>>4)*4+reg). Weights pre-split ONCE into frag order by lstm_prep
// -> per wave 16 coalesced dwordx4 loads, zero VALU. LDS planes frag-ordered,
// stage-slot == lane -> conflict-free. h packed u32 (2xbf16 hi+lo) plain
// loads/stores; c fp32 in d_ws (loads hoisted to kernel start).
// Reference bias swap preserved: f-gate uses b_o, o-gate uses b_f.

#define Bsz   1024
#define Tt    256
#define Hh    256
#define NCLS  10
#define NTHR  512
#define WSPN  32768                   // s16x8 frags per split plane (512 KB)

typedef float f32x4 __attribute__((ext_vector_type(4)));
typedef short s16x8 __attribute__((ext_vector_type(8)));
typedef unsigned int u32;

__device__ __forceinline__ unsigned short f2bf(float f) {   // RNE f32->bf16
    u32 u = __builtin_bit_cast(u32, f);
    return (unsigned short)((u + 0x7FFFu + ((u >> 16) & 1u)) >> 16);
}
__device__ __forceinline__ float bf2f(unsigned short b) {
    u32 u = ((u32)b) << 16;
    return __builtin_bit_cast(float, u);
}
template<int CTRL>
__device__ __forceinline__ float quadf(float v) {           // quad_perm bcast
    return __builtin_bit_cast(float,
        __builtin_amdgcn_update_dpp(0, __builtin_bit_cast(int, v),
                                    CTRL, 0xF, 0xF, true));
}
__device__ __forceinline__ float fast_tanh(float v) {
    const float e = __expf(-2.0f * fabsf(v));
    const float t = (1.0f - e) * __builtin_amdgcn_rcpf(1.0f + e);
    return copysignf(t, v);
}

// ---- prep: split fp32 weights into frag-ordered bf16 planes (runs once) ----
extern "C" __global__ void __launch_bounds__(256)
lstm_prep(const float* __restrict__ W_gh, const float* __restrict__ W_ih,
          const float* __restrict__ W_fh, const float* __restrict__ W_oh,
          short* __restrict__ wsp)
{
    const int idx  = blockIdx.x * 256 + threadIdx.x;   // ((cg*8+wv)*8+ks)*64+lane
    const int lane = idx & 63;
    const int ks   = (idx >> 6) & 7;
    const int wv   = (idx >> 9) & 7;
    const int cg   = idx >> 12;                        // 0..7
    const int gate = lane & 3;
    const int hcol_g = cg * 32 + wv * 4 + ((lane & 15) >> 2);
    const int krow = lane >> 4;
    const float* __restrict__ Wg =
        (gate == 0) ? W_gh : (gate == 1) ? W_ih : (gate == 2) ? W_fh : W_oh;
    s16x8 v1, v2;
    #pragma unroll
    for (int e = 0; e < 8; ++e) {
        const float w = Wg[(size_t)(ks * 32 + krow * 8 + e) * Hh + hcol_g];
        const unsigned short c1 = f2bf(w);
        const unsigned short c2 = f2bf(w - bf2f(c1));
        v1[e] = (short)c1; v2[e] = (short)c2;
    }
    *(s16x8*)(wsp + (size_t)idx * 8)          = v1;
    *(s16x8*)(wsp + (size_t)(WSPN + idx) * 8) = v2;
}

// ---- one timestep: h(t) -> h(t+1), c updated in place ----
extern "C" __global__ void __launch_bounds__(NTHR, 2)
lstm_step(const float* __restrict__ x,
          const float* __restrict__ W_gx, const float* __restrict__ b_g,
          const float* __restrict__ W_ix, const float* __restrict__ b_i,
          const float* __restrict__ W_fx, const float* __restrict__ b_f,
          const float* __restrict__ W_ox, const float* __restrict__ b_o,
          const short* __restrict__ wsp,
          const u32* __restrict__ hcur, u32* __restrict__ hnxt,
          float* __restrict__ cst, int t)
{
    __shared__ __align__(16) char smem[32768];   // 2 halves x (8K lo + 8K hi)

    const int tid  = threadIdx.x;
    const int lane = tid & 63;
    const int wv   = tid >> 6;              // 0..7 (MFMA col-tile AND k-slice)
    const int cg   = blockIdx.x & 7;        // colgroup: same-XCD blocks share it
    const int rg   = blockIdx.x >> 3;       // rowgroup (32 rows)
    const int r0   = rg * 32;

    const int gate   = lane & 3;
    const int hcol_g = cg * 32 + wv * 4 + ((lane & 15) >> 2);
    const int krow   = lane >> 4;

    // ---- weights: 16 coalesced dwordx4 frag loads, no VALU ----
    const s16x8* __restrict__ W1 =
        (const s16x8*)wsp + ((size_t)(cg * 8 + wv) * 8 * 64 + lane);
    s16x8 bw1[8], bw2[8];
    #pragma unroll
    for (int ks = 0; ks < 8; ++ks) {
        bw1[ks] = W1[ks * 64];
        bw2[ks] = W1[WSPN + ks * 64];
    }

    // per-gatecol constants (bias swap per reference)
    const float wx = ((gate == 0) ? W_gx : (gate == 1) ? W_ix : (gate == 2) ? W_fx : W_ox)[hcol_g];
    const float bb = ((gate == 0) ? b_g  : (gate == 1) ? b_i  : (gate == 2) ? b_o  : b_f )[hcol_g];

    // hoist c and x loads (independent of staging; overlap everything)
    float cold[2][4], xv[2][4];
    #pragma unroll
    for (int half = 0; half < 2; ++half)
        #pragma unroll
        for (int r = 0; r < 4; ++r) {
            const int row = r0 + half * 16 + krow * 4 + r;
            cold[half][r] = cst[(size_t)row * Hh + hcol_g];
            xv[half][r]   = x[(size_t)row * Tt + t];
        }

    // ---- stage h(t): both halves, slot == lane (conflict-free) ----
    const int sr = lane & 15;               // row within half
    const int c8 = (lane >> 4) * 8;         // u32 col within 32-col slice
    #pragma unroll
    for (int half = 0; half < 2; ++half) {
        const u32* src = hcur + (size_t)(r0 + half * 16 + sr) * Hh + wv * 32 + c8;
        const uint4 a = *(const uint4*)src;
        const uint4 b = *(const uint4*)(src + 4);
        u32 lo[4], hi[4];
        lo[0] = (a.x & 0xffffu) | (a.y << 16);  hi[0] = (a.x >> 16) | (a.y & 0xffff0000u);
        lo[1] = (a.z & 0xffffu) | (a.w << 16);  hi[1] = (a.z >> 16) | (a.w & 0xffff0000u);
        lo[2] = (b.x & 0xffffu) | (b.y << 16);  hi[2] = (b.x >> 16) | (b.y & 0xffff0000u);
        lo[3] = (b.z & 0xffffu) | (b.w << 16);  hi[3] = (b.z >> 16) | (b.w & 0xffff0000u);
        char* pb = smem + half * 16384 + wv * 1024 + lane * 16;
        *(uint4*)pb          = *(uint4*)lo;
        *(uint4*)(pb + 8192) = *(uint4*)hi;
    }
    __syncthreads();

    // ---- per half: 24 MFMA (3 indep chains) + phase B ----
    #pragma unroll
    for (int half = 0; half < 2; ++half) {
        f32x4 aA = {0.f,0.f,0.f,0.f}, aB = {0.f,0.f,0.f,0.f}, aC = {0.f,0.f,0.f,0.f};
        #pragma unroll
        for (int ks = 0; ks < 8; ++ks) {
            const char* ab = smem + half * 16384 + ks * 1024 + lane * 16;
            const s16x8 a1 = *(const s16x8*)ab;
            const s16x8 a2 = *(const s16x8*)(ab + 8192);
            aA = __builtin_amdgcn_mfma_f32_16x16x32_bf16(a1, bw1[ks], aA, 0, 0, 0);
            aB = __builtin_amdgcn_mfma_f32_16x16x32_bf16(a2, bw1[ks], aB, 0, 0, 0);
            aC = __builtin_amdgcn_mfma_f32_16x16x32_bf16(a1, bw2[ks], aC, 0, 0, 0);
        }
        const f32x4 acc = aA + aB + aC;

        #pragma unroll
        for (int r = 0; r < 4; ++r) {
            const int row = r0 + half * 16 + krow * 4 + r;
            const float pre = acc[r] + fmaf(xv[half][r], wx, bb);
            const float vin = (gate == 0) ? 2.0f * pre : pre;
            const float e   = __expf(-fabsf(vin));
            const float rc  = __builtin_amdgcn_rcpf(1.0f + e);
            const float sig = (vin >= 0.0f) ? rc : 1.0f - rc;
            const float th  = copysignf((1.0f - e) * rc, pre);
            const float act = (gate == 0) ? th : sig;
            const float gv = quadf<0x00>(act);
            const float iv = quadf<0x55>(act);
            const float fv = quadf<0xAA>(act);
            const float ov = quadf<0xFF>(act);
            const float cnew = fmaf(gv, iv, cold[half][r] * fv);
            const float hv   = fast_tanh(cnew) * ov;
            if (gate == 0) {
                cst[(size_t)row * Hh + hcol_g] = cnew;
                const unsigned short h1 = f2bf(hv);
                const unsigned short h2 = f2bf(hv - bf2f(h1));
                hnxt[(size_t)row * Hh + hcol_g] = (u32)h1 | ((u32)h2 << 16);
            }
        }
    }
}

// ---- classifier: out = h_T @ W_ph + b_p ----
extern "C" __global__ void __launch_bounds__(256)
lstm_head(const u32* __restrict__ hT, const float* __restrict__ W_ph,
          const float* __restrict__ b_p, float* __restrict__ out)
{
    __shared__ u32 tile[32 * Hh];           // 32 KB
    const int tid = threadIdx.x;
    const int r0  = blockIdx.x * 32;
    for (int i = tid; i < 32 * Hh; i += 256)
        tile[i] = hT[(size_t)r0 * Hh + i];
    __syncthreads();
    for (int idx = tid; idx < 32 * NCLS; idx += 256) {
        const int row = idx / NCLS;
        const int cc  = idx - row * NCLS;
        float a = b_p[cc];
        for (int k = 0; k < Hh; ++k) {
            const u32 p = tile[row * Hh + k];
            a = fmaf(bf2f((unsigned short)p) + bf2f((unsigned short)(p >> 16)),
                     W_ph[k * NCLS + cc], a);
        }
        out[(size_t)(r0 + row) * NCLS + cc] = a;
    }
}

extern "C" void kernel_launch(void* const* d_in, const int* in_sizes, int n_in,
                              void* d_out, int out_size, void* d_ws, size_t ws_size,
                              hipStream_t stream) {
    const float* x    = (const float*)d_in[0];
    const float* W_gx = (const float*)d_in[1];
    const float* W_gh = (const float*)d_in[2];
    const float* b_g  = (const float*)d_in[3];
    const float* W_ix = (const float*)d_in[4];
    const float* W_ih = (const float*)d_in[5];
    const float* b_i  = (const float*)d_in[6];
    const float* W_fx = (const float*)d_in[7];
    const float* W_fh = (const float*)d_in[8];
    const float* b_f  = (const float*)d_in[9];
    const float* W_ox = (const float*)d_in[10];
    const float* W_oh = (const float*)d_in[11];
    const float* b_o  = (const float*)d_in[12];
    const float* W_ph = (const float*)d_in[13];
    const float* b_p  = (const float*)d_in[14];
    float* out = (float*)d_out;

    // d_ws layout: hbuf0 1MB | hbuf1 1MB | c 1MB | wsp 1MB
    u32*   hbuf0 = (u32*)d_ws;
    u32*   hbuf1 = (u32*)((char*)d_ws + (1u << 20));
    float* cst   = (float*)((char*)d_ws + (2u << 20));
    short* wsp   = (short*)((char*)d_ws + (3u << 20));

    // zero h(0) (buffer 0) and c
    hipMemsetAsync(d_ws, 0, 3u << 20, stream);

    lstm_prep<<<dim3(128), dim3(256), 0, stream>>>(W_gh, W_ih, W_fh, W_oh, wsp);

    for (int t = 0; t < Tt; ++t) {
        const u32* hcur = (t & 1) ? hbuf1 : hbuf0;
        u32*       hnxt = (t & 1) ? hbuf0 : hbuf1;
        lstm_step<<<dim3(256), dim3(NTHR), 0, stream>>>(
            x, W_gx, b_g, W_ix, b_i, W_fx, b_f, W_ox, b_o,
            wsp, hcur, hnxt, cst, t);
    }

    // h(256) lives in buffer (256&1)==0 -> hbuf0
    lstm_head<<<dim3(32), dim3(256), 0, stream>>>(hbuf0, W_ph, b_p, out);
}